// Round 8
// baseline (206.425 us; speedup 1.0000x reference)
//
#include <hip/hip_runtime.h>
#include <hip/hip_bf16.h>

#define BB 8
#define NP 4096
#define STRIDE 4
#define KNN 32
#define NS (NP/STRIDE)      // 1024
#define NQ (BB*NS)          // 8192
#define DIN 67
#define H1N 128
#define H2N 256
#define SCAPW 1024          // survivor cap per wave (query)

typedef __attribute__((ext_vector_type(8)))  short bf16x8;
typedef __attribute__((ext_vector_type(16))) float f32x16;
typedef __attribute__((ext_vector_type(8)))  short short8;

// ---------- helpers ----------
__device__ __forceinline__ unsigned int f2u(float f) {
    unsigned int b = __float_as_uint(f);
    return (b & 0x80000000u) ? ~b : (b | 0x80000000u);
}
__device__ __forceinline__ short f2bf(float f) {   // RNE float->bf16 bits
    unsigned u = __float_as_uint(f);
    unsigned r = u + 0x7FFFu + ((u >> 16) & 1u);
    return (short)(r >> 16);
}

// ---------- KNN: wave-autonomous (1 wave = 1 query, ZERO __syncthreads) ----------
__global__ __launch_bounds__(256) void knn_kernel(const float* __restrict__ pos,
                                                  int* __restrict__ col,
                                                  float* __restrict__ out) {
    __shared__ __align__(16) unsigned long long surv[4][SCAPW];   // 32 KB

    const int t    = threadIdx.x;
    const int w    = t >> 6;
    const int lane = t & 63;
    const int q    = blockIdx.x * 4 + w;
    const int b    = q >> 10;
    const int s    = q & (NS - 1);
    const int qi   = b * NP + s * STRIDE;

    const float qx = pos[qi*3+0], qy = pos[qi*3+1], qz = pos[qi*3+2];
    const float q2 = __fadd_rn(__fadd_rn(__fmul_rn(qx,qx), __fmul_rn(qy,qy)), __fmul_rn(qz,qz));
    const float* pb = pos + (size_t)b * NP * 3;

    // folded tail outputs: wave writes its query's pos/batch/idx
    {
        float* pos_out   = out + (size_t)NQ * H2N;
        float* batch_out = pos_out + (size_t)NQ * 3;
        float* idx_out   = batch_out + NQ;
        if (lane < 3)       pos_out[q*3+lane] = pos[qi*3+lane];
        else if (lane == 3) batch_out[q] = (float)b;
        else if (lane == 4) idx_out[q]   = (float)qi;
    }

    // ---- sample pass: key of point lane*64, exact reference rounding ----
    unsigned int skey;
    {
        const int n = lane * 64;
        const float px = pb[n*3+0], py = pb[n*3+1], pz = pb[n*3+2];
        const float p2 = __fadd_rn(__fadd_rn(__fmul_rn(px,px), __fmul_rn(py,py)), __fmul_rn(pz,pz));
        const float dt = __fadd_rn(__fadd_rn(__fmul_rn(qx,px), __fmul_rn(qy,py)), __fmul_rn(qz,pz));
        skey = f2u(__fsub_rn(__fadd_rn(q2, p2), __fmul_rn(2.0f, dt)));
    }
    int srk = 0;
    #pragma unroll
    for (int ss = 0; ss < 64; ++ss) {
        const unsigned int ks = (unsigned int)__shfl((int)skey, ss, 64);
        srk += (int)((ks < skey) | ((ks == skey) & (ss < lane)));
    }
    // pivot thresholds at sample-ranks {0,1,3,8,31} (ranks unique -> exactly one lane each)
    unsigned int T0, T1, T2, T3, T4;
    {
        unsigned long long m;
        m = __ballot(srk == 0);  T0 = (unsigned int)__shfl((int)skey, (int)__builtin_ctzll(m), 64);
        m = __ballot(srk == 1);  T1 = (unsigned int)__shfl((int)skey, (int)__builtin_ctzll(m), 64);
        m = __ballot(srk == 3);  T2 = (unsigned int)__shfl((int)skey, (int)__builtin_ctzll(m), 64);
        m = __ballot(srk == 8);  T3 = (unsigned int)__shfl((int)skey, (int)__builtin_ctzll(m), 64);
        m = __ballot(srk == 31); T4 = (unsigned int)__shfl((int)skey, (int)__builtin_ctzll(m), 64);
    }

    unsigned long long* sw = surv[w];

    // single-pass ballot compact at threshold T (wave-private, no atomics/barriers)
    auto compact = [&](unsigned int T) -> int {
        int base = 0;
        #pragma unroll 4
        for (int j4 = 0; j4 < 16; ++j4) {
            const int n0 = j4 * 256 + lane * 4;
            const float4* pp = (const float4*)(pb + (size_t)n0 * 3);
            const float4 v0 = pp[0], v1 = pp[1], v2 = pp[2];
            const float px[4] = {v0.x, v0.w, v1.z, v2.y};
            const float py[4] = {v0.y, v1.x, v1.w, v2.z};
            const float pz[4] = {v0.z, v1.y, v2.x, v2.w};
            #pragma unroll
            for (int jj = 0; jj < 4; ++jj) {
                const float p2 = __fadd_rn(__fadd_rn(__fmul_rn(px[jj],px[jj]), __fmul_rn(py[jj],py[jj])), __fmul_rn(pz[jj],pz[jj]));
                const float dt = __fadd_rn(__fadd_rn(__fmul_rn(qx,px[jj]), __fmul_rn(qy,py[jj])), __fmul_rn(qz,pz[jj]));
                const unsigned int k = f2u(__fsub_rn(__fadd_rn(q2, p2), __fmul_rn(2.0f, dt)));
                const bool psel = (k <= T);
                const unsigned long long mask = __ballot(psel);
                if (psel) {
                    const int idx = base + (int)__popcll(mask & ((1ull << lane) - 1ull));
                    if (idx < SCAPW)
                        sw[idx] = ((unsigned long long)k << 32) | (unsigned int)(n0 + jj);
                }
                base += (int)__popcll(mask);
            }
        }
        return base;
    };

    // escalation ladder (wave-uniform decisions); expected 1.09 passes
    int lvl = 1, C = 0;
    #pragma unroll 1
    for (int att = 0; att < 4; ++att) {
        const unsigned int T = (lvl == 0) ? T0 : (lvl == 1) ? T1 : (lvl == 2) ? T2 : (lvl == 3) ? T3 : T4;
        C = compact(T);
        if (C >= KNN && C <= SCAPW) break;
        if (C < KNN) { if (lvl >= 4) break; ++lvl; }
        else         { if (lvl == 0) break; lvl = 0; }
    }
    if (C > SCAPW) C = SCAPW;   // pathological clamp (~1e-12)

    // flat exact-rank pass (same-wave LDS -> no barrier; u64 = (key,idx) reference tie order)
    const ulonglong2* sp2 = (const ulonglong2*)sw;
    const int C2 = C >> 1;
    for (int j = lane; j < C; j += 64) {
        const unsigned long long v = sw[j];
        int rk = 0;
        #pragma unroll 4
        for (int ss = 0; ss < C2; ++ss) {
            const ulonglong2 pr = sp2[ss];          // broadcast read, conflict-free
            rk += (int)(pr.x < v) + (int)(pr.y < v);
        }
        if (C & 1) rk += (int)(sw[C - 1] < v);
        if (rk < KNN)
            col[q * KNN + rk] = b * NP + (int)(unsigned int)(v & 0xFFFFFFFFull);
    }
}

// ---------- merged weight prep: frag-linear bf16 layouts ----------
__global__ __launch_bounds__(64) void prep_w(const float* __restrict__ W1,
                                             const float* __restrict__ W2,
                                             short* __restrict__ W1T,
                                             short* __restrict__ W2T) {
    const int l = threadIdx.x;
    if (blockIdx.x < 20) {
        const int nt = blockIdx.x / 5, t = blockIdx.x % 5;
        const int c  = 32*nt + (l & 31);
        short8 v;
        #pragma unroll
        for (int b = 0; b < 8; ++b) {
            const int k = 16*t + 8*(l >> 5) + b;
            v[b] = (k < DIN) ? f2bf(W1[k * H1N + c]) : (short)0;
        }
        *(short8*)(W1T + ((size_t)(nt*5 + t) * 64 + l) * 8) = v;
    } else {
        const int bb = blockIdx.x - 20;
        const int nt = bb >> 3, t = bb & 7;
        const int c  = 32*nt + (l & 31);
        short8 v;
        #pragma unroll
        for (int b = 0; b < 8; ++b) {
            const int k = 16*t + 8*(l >> 5) + b;
            v[b] = f2bf(W2[k * H2N + c]);
        }
        *(short8*)(W2T + ((size_t)(nt*8 + t) * 64 + l) * 8) = v;
    }
}

// ---------- fused MFMA MLP: 4 queries/block, wave = query (unchanged) ----------
__global__ __launch_bounds__(256, 2) void mlp_mfma(const float* __restrict__ x,
                                                   const float* __restrict__ pos,
                                                   const int* __restrict__ col,
                                                   const float* __restrict__ b1,
                                                   const float* __restrict__ b2,
                                                   const short* __restrict__ W1T,
                                                   const short* __restrict__ W2T,
                                                   float* __restrict__ out) {
    __shared__ __align__(16) short feat[128 * 80];    // 20480 B
    __shared__ __align__(16) short h1s [128 * 128];   // 32768 B, XOR-swizzled slots

    const int q0 = blockIdx.x * 4;
    const int t  = threadIdx.x;
    const int w  = t >> 6, l = t & 63;

    // gather: row = t>>1 (0..127), part = t&1 covers 32 x-floats
    {
        const int row  = t >> 1, part = t & 1;
        const int q    = q0 + (row >> 5);
        const int c    = col[q * KNN + (row & 31)];
        const float4* xr = (const float4*)(x + (size_t)c * 64 + part * 32);
        short* fr = feat + row * 80 + part * 32;
        #pragma unroll
        for (int i = 0; i < 8; ++i) {
            const float4 v = xr[i];
            *(int*)(fr + i * 4 + 0) = (int)((unsigned short)f2bf(v.x) | ((unsigned)(unsigned short)f2bf(v.y) << 16));
            *(int*)(fr + i * 4 + 2) = (int)((unsigned short)f2bf(v.z) | ((unsigned)(unsigned short)f2bf(v.w) << 16));
        }
        if (part == 0) {
            const int b  = q >> 10;
            const int qi = b * NP + (q & (NS - 1)) * STRIDE;
            short8 o;
            o[0] = f2bf(pos[c*3+0] - pos[qi*3+0]);
            o[1] = f2bf(pos[c*3+1] - pos[qi*3+1]);
            o[2] = f2bf(pos[c*3+2] - pos[qi*3+2]);
            o[3] = 0; o[4] = 0; o[5] = 0; o[6] = 0; o[7] = 0;
            *(short8*)(feat + row * 80 + 64) = o;
            short8 z = {0,0,0,0,0,0,0,0};
            *(short8*)(feat + row * 80 + 72) = z;
        }
    }
    __syncthreads();

    const int lr = l & 31;   // row-within-tile / col lane
    const int lh = l >> 5;   // k-half selector

    // layer 1: h1 = relu(feat @ W1 + b1)
    {
        bf16x8 w1f[20];
        #pragma unroll
        for (int i = 0; i < 20; ++i)
            w1f[i] = *(const bf16x8*)(W1T + ((size_t)i * 64 + l) * 8);

        bf16x8 a1[5];
        #pragma unroll
        for (int kt = 0; kt < 5; ++kt) {
            const int row = 32*w + lr;
            a1[kt] = *(const bf16x8*)(feat + row * 80 + 16*kt + 8*lh);
        }

        #pragma unroll
        for (int nt = 0; nt < 4; ++nt) {
            const float bv = b1[32*nt + lr];
            f32x16 acc;
            #pragma unroll
            for (int r = 0; r < 16; ++r) acc[r] = bv;
            #pragma unroll
            for (int kt = 0; kt < 5; ++kt)
                acc = __builtin_amdgcn_mfma_f32_32x32x16_bf16(a1[kt], w1f[nt*5 + kt], acc, 0, 0, 0);
            #pragma unroll
            for (int r = 0; r < 16; ++r) {
                const int i   = (r & 3) + 8*(r >> 2) + 4*lh;
                const int row = 32*w + i;
                const int c   = 32*nt + lr;
                const int adr = row * 128 + ((((c >> 3) ^ (row & 15)) << 3) | (c & 7));
                h1s[adr] = f2bf(fmaxf(acc[r], 0.0f));
            }
        }
    }
    __syncthreads();

    // layer 2: h2 = h1 @ W2 (+b2, relu after max), maxpool over 32 rows
    {
        bf16x8 a2[8];
        #pragma unroll
        for (int kt = 0; kt < 8; ++kt) {
            const int row  = 32*w + lr;
            const int slot = 2*kt + lh;
            a2[kt] = *(const bf16x8*)(h1s + row * 128 + ((slot ^ (row & 15)) << 3));
        }

        f32x16 acc[8];
        #pragma unroll
        for (int nt = 0; nt < 8; ++nt)
            #pragma unroll
            for (int r = 0; r < 16; ++r) acc[nt][r] = 0.0f;

        bf16x8 cur[8];
        #pragma unroll
        for (int kt = 0; kt < 8; ++kt)
            cur[kt] = *(const bf16x8*)(W2T + ((size_t)kt * 64 + l) * 8);

        #pragma unroll
        for (int nt = 0; nt < 8; ++nt) {
            bf16x8 nxt[8];
            if (nt < 7) {
                #pragma unroll
                for (int kt = 0; kt < 8; ++kt)
                    nxt[kt] = *(const bf16x8*)(W2T + ((size_t)((nt+1)*8 + kt) * 64 + l) * 8);
            }
            #pragma unroll
            for (int kt = 0; kt < 8; ++kt)
                acc[nt] = __builtin_amdgcn_mfma_f32_32x32x16_bf16(a2[kt], cur[kt], acc[nt], 0, 0, 0);
            #pragma unroll
            for (int kt = 0; kt < 8; ++kt) cur[kt] = nxt[kt];
        }

        const int q = q0 + w;
        #pragma unroll
        for (int nt = 0; nt < 8; ++nt) {
            float m = acc[nt][0];
            #pragma unroll
            for (int r = 1; r < 16; ++r) m = fmaxf(m, acc[nt][r]);
            m = fmaxf(m, __shfl_xor(m, 32, 64));
            m = fmaxf(m + b2[32*nt + lr], 0.0f);
            if (l < 32) out[(size_t)q * H2N + 32*nt + l] = m;
        }
    }
}

extern "C" void kernel_launch(void* const* d_in, const int* in_sizes, int n_in,
                              void* d_out, int out_size, void* d_ws, size_t ws_size,
                              hipStream_t stream) {
    const float* x   = (const float*)d_in[0];
    const float* pos = (const float*)d_in[1];
    const float* W1  = (const float*)d_in[3];
    const float* b1  = (const float*)d_in[4];
    const float* W2  = (const float*)d_in[5];
    const float* b2  = (const float*)d_in[6];
    float* out = (float*)d_out;

    char* ws   = (char*)d_ws;
    int*  col  = (int*)ws;                               // 1 MB
    short* W1T = (short*)(ws + 1048576);                 // 20480 B
    short* W2T = (short*)(ws + 1048576 + 20480);         // 65536 B

    prep_w<<<84, 64, 0, stream>>>(W1, W2, W1T, W2T);
    knn_kernel<<<NQ/4, 256, 0, stream>>>(pos, col, out);
    mlp_mfma<<<NQ/4, 256, 0, stream>>>(x, pos, col, b1, b2, W1T, W2T, out);
}

// Round 9
// 154.947 us; speedup vs baseline: 1.3322x; 1.3322x over previous
//
#include <hip/hip_runtime.h>
#include <hip/hip_bf16.h>

#define BB 8
#define NP 4096
#define STRIDE 4
#define KNN 32
#define NS (NP/STRIDE)      // 1024
#define NQ (BB*NS)          // 8192
#define DIN 67
#define H1N 128
#define H2N 256
#define WCAP 512            // survivor cap per wave segment

typedef __attribute__((ext_vector_type(8)))  short bf16x8;
typedef __attribute__((ext_vector_type(16))) float f32x16;
typedef __attribute__((ext_vector_type(8)))  short short8;

// ---------- helpers ----------
__device__ __forceinline__ unsigned int f2u(float f) {
    unsigned int b = __float_as_uint(f);
    return (b & 0x80000000u) ? ~b : (b | 0x80000000u);
}
__device__ __forceinline__ short f2bf(float f) {   // RNE float->bf16 bits
    unsigned u = __float_as_uint(f);
    unsigned r = u + 0x7FFFu + ((u >> 16) & 1u);
    return (short)(r >> 16);
}

// ---------- KNN: round-7 base + write-first compact + 16KB LDS + folded tail ----------
__global__ __launch_bounds__(256) void knn_kernel(const float* __restrict__ pos,
                                                  int* __restrict__ col,
                                                  float* __restrict__ out) {
    __shared__ __align__(16) unsigned long long surv[4 * WCAP];   // 16 KB
    __shared__ unsigned int pvt[4];
    __shared__ int cnts[4];

    const int q    = blockIdx.x;
    const int b    = q >> 10;
    const int s    = q & (NS - 1);
    const int qi   = b * NP + s * STRIDE;
    const int t    = threadIdx.x;
    const int w    = t >> 6;
    const int lane = t & 63;

    if (t == 128) pvt[3] = 0xFFFFFFFFu;     // guaranteed fallback threshold

    // folded tail outputs (one block per query)
    if (t < 5) {
        float* pos_out   = out + (size_t)NQ * H2N;
        float* batch_out = pos_out + (size_t)NQ * 3;
        float* idx_out   = batch_out + NQ;
        if (t < 3)       pos_out[q*3+t] = pos[qi*3+t];
        else if (t == 3) batch_out[q] = (float)b;
        else             idx_out[q]   = (float)qi;
    }

    const float qx = pos[qi*3+0], qy = pos[qi*3+1], qz = pos[qi*3+2];
    const float q2 = __fadd_rn(__fadd_rn(__fmul_rn(qx,qx), __fmul_rn(qy,qy)), __fmul_rn(qz,qz));

    // distance phase: thread handles 4 consecutive points per group (3x float4), exact ref rounding
    const float* pb = pos + (size_t)b * NP * 3;
    unsigned int myk[16];
    #pragma unroll
    for (int i = 0; i < 4; ++i) {
        const int u = t + i * 256;
        const float4* pp = (const float4*)(pb + (size_t)u * 12);
        const float4 v0 = pp[0], v1 = pp[1], v2 = pp[2];
        const float px[4] = {v0.x, v0.w, v1.z, v2.y};
        const float py[4] = {v0.y, v1.x, v1.w, v2.z};
        const float pz[4] = {v0.z, v1.y, v2.x, v2.w};
        #pragma unroll
        for (int j = 0; j < 4; ++j) {
            const float p2 = __fadd_rn(__fadd_rn(__fmul_rn(px[j],px[j]), __fmul_rn(py[j],py[j])), __fmul_rn(pz[j],pz[j]));
            const float dt = __fadd_rn(__fadd_rn(__fmul_rn(qx,px[j]), __fmul_rn(qy,py[j])), __fmul_rn(qz,pz[j]));
            const float d2 = __fsub_rn(__fadd_rn(q2, p2), __fmul_rn(2.0f, dt));
            myk[i*4+j] = f2u(d2);
        }
    }

    // pivot: wave 0 ranks its 64 myk[0] keys (points 4t) via shfl ladder
    if (t < 64) {
        const unsigned int mk = myk[0];
        int rank = 0;
        #pragma unroll
        for (int ss = 0; ss < 64; ++ss) {
            const unsigned int ks = (unsigned int)__shfl((int)mk, ss, 64);
            rank += (int)((ks < mk) | ((ks == mk) & (ss < t)));
        }
        if (rank == 1)  pvt[0] = mk;   // E[C] ~ 126
        if (rank == 3)  pvt[1] = mk;   // E[C] ~ 252
        if (rank == 8)  pvt[2] = mk;   // E[C] ~ 535
    }
    __syncthreads();

    // write-first compact at level 0 (per-wave segment, register prefix, no atomics)
    int level = 0;
    {
        const unsigned int T = pvt[0];
        int base = 0;
        #pragma unroll
        for (int i = 0; i < 16; ++i) {
            const bool p = (myk[i] <= T);
            const unsigned long long mask = __ballot(p);
            if (p) {
                const int off = base + (int)__popcll(mask & ((1ull << lane) - 1ull));
                if (off < WCAP) {
                    const int n = 4 * (t + (i >> 2) * 256) + (i & 3);
                    surv[(w << 9) + off] = ((unsigned long long)myk[i] << 32) | (unsigned int)n;
                }
            }
            base += (int)__popcll(mask);
        }
        if (lane == 0) cnts[w] = (base < WCAP) ? base : WCAP;
    }
    __syncthreads();

    int c0 = cnts[0], c1 = cnts[1], c2 = cnts[2], c3 = cnts[3];
    int C = c0 + c1 + c2 + c3;

    // rare escalation: count-ladder up, then one rewrite (block-uniform)
    if (C < KNN) {
        for (level = 1; level < 4; ++level) {
            const unsigned int T = pvt[level];
            int cw = 0;
            #pragma unroll
            for (int i = 0; i < 16; ++i)
                cw += (int)__popcll(__ballot(myk[i] <= T));
            if (lane == 0) cnts[w] = cw;
            __syncthreads();
            C = cnts[0] + cnts[1] + cnts[2] + cnts[3];
            if (C >= KNN) break;
            __syncthreads();
        }
        __syncthreads();
        {
            const unsigned int T = pvt[level];
            int base = 0;
            #pragma unroll
            for (int i = 0; i < 16; ++i) {
                const bool p = (myk[i] <= T);
                const unsigned long long mask = __ballot(p);
                if (p) {
                    const int off = base + (int)__popcll(mask & ((1ull << lane) - 1ull));
                    if (off < WCAP) {
                        const int n = 4 * (t + (i >> 2) * 256) + (i & 3);
                        surv[(w << 9) + off] = ((unsigned long long)myk[i] << 32) | (unsigned int)n;
                    }
                }
                base += (int)__popcll(mask);
            }
            if (lane == 0) cnts[w] = (base < WCAP) ? base : WCAP;
        }
        __syncthreads();
        c0 = cnts[0]; c1 = cnts[1]; c2 = cnts[2]; c3 = cnts[3];
        C = c0 + c1 + c2 + c3;
    }

    // flat exact-rank pass over the 4 segments (u64 = (key, index) reference tie order)
    const int s1 = c0, s2 = c0 + c1, s3 = c0 + c1 + c2;
    const int cseg[4] = {c0, c1, c2, c3};
    for (int j = t; j < C; j += 256) {
        const int seg = (int)(j >= s1) + (int)(j >= s2) + (int)(j >= s3);
        const int off = j - ((seg == 0) ? 0 : (seg == 1) ? s1 : (seg == 2) ? s2 : s3);
        const unsigned long long v = surv[(seg << 9) + off];
        int rk = 0;
        #pragma unroll 1
        for (int k = 0; k < 4; ++k) {
            const ulonglong2* sp2 = (const ulonglong2*)(surv + (k << 9));
            const int ck = cseg[k];
            const int ck2 = ck >> 1;
            #pragma unroll 4
            for (int ss = 0; ss < ck2; ++ss) {
                const ulonglong2 pr = sp2[ss];
                rk += (int)(pr.x < v) + (int)(pr.y < v);
            }
            if (ck & 1) rk += (int)(surv[(k << 9) + ck - 1] < v);
        }
        if (rk < KNN)
            col[q * KNN + rk] = b * NP + (int)(unsigned int)(v & 0xFFFFFFFFull);
    }
}

// ---------- merged weight prep: frag-linear bf16 layouts ----------
__global__ __launch_bounds__(64) void prep_w(const float* __restrict__ W1,
                                             const float* __restrict__ W2,
                                             short* __restrict__ W1T,
                                             short* __restrict__ W2T) {
    const int l = threadIdx.x;
    if (blockIdx.x < 20) {
        const int nt = blockIdx.x / 5, t = blockIdx.x % 5;
        const int c  = 32*nt + (l & 31);
        short8 v;
        #pragma unroll
        for (int b = 0; b < 8; ++b) {
            const int k = 16*t + 8*(l >> 5) + b;
            v[b] = (k < DIN) ? f2bf(W1[k * H1N + c]) : (short)0;
        }
        *(short8*)(W1T + ((size_t)(nt*5 + t) * 64 + l) * 8) = v;
    } else {
        const int bb = blockIdx.x - 20;
        const int nt = bb >> 3, t = bb & 7;
        const int c  = 32*nt + (l & 31);
        short8 v;
        #pragma unroll
        for (int b = 0; b < 8; ++b) {
            const int k = 16*t + 8*(l >> 5) + b;
            v[b] = f2bf(W2[k * H2N + c]);
        }
        *(short8*)(W2T + ((size_t)(nt*8 + t) * 64 + l) * 8) = v;
    }
}

// ---------- fused MFMA MLP: 4 queries/block, wave = query (unchanged, round-7) ----------
__global__ __launch_bounds__(256, 2) void mlp_mfma(const float* __restrict__ x,
                                                   const float* __restrict__ pos,
                                                   const int* __restrict__ col,
                                                   const float* __restrict__ b1,
                                                   const float* __restrict__ b2,
                                                   const short* __restrict__ W1T,
                                                   const short* __restrict__ W2T,
                                                   float* __restrict__ out) {
    __shared__ __align__(16) short feat[128 * 80];    // 20480 B
    __shared__ __align__(16) short h1s [128 * 128];   // 32768 B, XOR-swizzled slots

    const int q0 = blockIdx.x * 4;
    const int t  = threadIdx.x;
    const int w  = t >> 6, l = t & 63;

    // gather: row = t>>1 (0..127), part = t&1 covers 32 x-floats
    {
        const int row  = t >> 1, part = t & 1;
        const int q    = q0 + (row >> 5);
        const int c    = col[q * KNN + (row & 31)];
        const float4* xr = (const float4*)(x + (size_t)c * 64 + part * 32);
        short* fr = feat + row * 80 + part * 32;
        #pragma unroll
        for (int i = 0; i < 8; ++i) {
            const float4 v = xr[i];
            *(int*)(fr + i * 4 + 0) = (int)((unsigned short)f2bf(v.x) | ((unsigned)(unsigned short)f2bf(v.y) << 16));
            *(int*)(fr + i * 4 + 2) = (int)((unsigned short)f2bf(v.z) | ((unsigned)(unsigned short)f2bf(v.w) << 16));
        }
        if (part == 0) {
            const int b  = q >> 10;
            const int qi = b * NP + (q & (NS - 1)) * STRIDE;
            short8 o;
            o[0] = f2bf(pos[c*3+0] - pos[qi*3+0]);
            o[1] = f2bf(pos[c*3+1] - pos[qi*3+1]);
            o[2] = f2bf(pos[c*3+2] - pos[qi*3+2]);
            o[3] = 0; o[4] = 0; o[5] = 0; o[6] = 0; o[7] = 0;
            *(short8*)(feat + row * 80 + 64) = o;
            short8 z = {0,0,0,0,0,0,0,0};
            *(short8*)(feat + row * 80 + 72) = z;
        }
    }
    __syncthreads();

    const int lr = l & 31;   // row-within-tile / col lane
    const int lh = l >> 5;   // k-half selector

    // layer 1: h1 = relu(feat @ W1 + b1)
    {
        bf16x8 w1f[20];
        #pragma unroll
        for (int i = 0; i < 20; ++i)
            w1f[i] = *(const bf16x8*)(W1T + ((size_t)i * 64 + l) * 8);

        bf16x8 a1[5];
        #pragma unroll
        for (int kt = 0; kt < 5; ++kt) {
            const int row = 32*w + lr;
            a1[kt] = *(const bf16x8*)(feat + row * 80 + 16*kt + 8*lh);
        }

        #pragma unroll
        for (int nt = 0; nt < 4; ++nt) {
            const float bv = b1[32*nt + lr];
            f32x16 acc;
            #pragma unroll
            for (int r = 0; r < 16; ++r) acc[r] = bv;
            #pragma unroll
            for (int kt = 0; kt < 5; ++kt)
                acc = __builtin_amdgcn_mfma_f32_32x32x16_bf16(a1[kt], w1f[nt*5 + kt], acc, 0, 0, 0);
            #pragma unroll
            for (int r = 0; r < 16; ++r) {
                const int i   = (r & 3) + 8*(r >> 2) + 4*lh;
                const int row = 32*w + i;
                const int c   = 32*nt + lr;
                const int adr = row * 128 + ((((c >> 3) ^ (row & 15)) << 3) | (c & 7));
                h1s[adr] = f2bf(fmaxf(acc[r], 0.0f));
            }
        }
    }
    __syncthreads();

    // layer 2: h2 = h1 @ W2 (+b2, relu after max), maxpool over 32 rows
    {
        bf16x8 a2[8];
        #pragma unroll
        for (int kt = 0; kt < 8; ++kt) {
            const int row  = 32*w + lr;
            const int slot = 2*kt + lh;
            a2[kt] = *(const bf16x8*)(h1s + row * 128 + ((slot ^ (row & 15)) << 3));
        }

        f32x16 acc[8];
        #pragma unroll
        for (int nt = 0; nt < 8; ++nt)
            #pragma unroll
            for (int r = 0; r < 16; ++r) acc[nt][r] = 0.0f;

        bf16x8 cur[8];
        #pragma unroll
        for (int kt = 0; kt < 8; ++kt)
            cur[kt] = *(const bf16x8*)(W2T + ((size_t)kt * 64 + l) * 8);

        #pragma unroll
        for (int nt = 0; nt < 8; ++nt) {
            bf16x8 nxt[8];
            if (nt < 7) {
                #pragma unroll
                for (int kt = 0; kt < 8; ++kt)
                    nxt[kt] = *(const bf16x8*)(W2T + ((size_t)((nt+1)*8 + kt) * 64 + l) * 8);
            }
            #pragma unroll
            for (int kt = 0; kt < 8; ++kt)
                acc[nt] = __builtin_amdgcn_mfma_f32_32x32x16_bf16(a2[kt], cur[kt], acc[nt], 0, 0, 0);
            #pragma unroll
            for (int kt = 0; kt < 8; ++kt) cur[kt] = nxt[kt];
        }

        const int q = q0 + w;
        #pragma unroll
        for (int nt = 0; nt < 8; ++nt) {
            float m = acc[nt][0];
            #pragma unroll
            for (int r = 1; r < 16; ++r) m = fmaxf(m, acc[nt][r]);
            m = fmaxf(m, __shfl_xor(m, 32, 64));
            m = fmaxf(m + b2[32*nt + lr], 0.0f);
            if (l < 32) out[(size_t)q * H2N + 32*nt + l] = m;
        }
    }
}

extern "C" void kernel_launch(void* const* d_in, const int* in_sizes, int n_in,
                              void* d_out, int out_size, void* d_ws, size_t ws_size,
                              hipStream_t stream) {
    const float* x   = (const float*)d_in[0];
    const float* pos = (const float*)d_in[1];
    const float* W1  = (const float*)d_in[3];
    const float* b1  = (const float*)d_in[4];
    const float* W2  = (const float*)d_in[5];
    const float* b2  = (const float*)d_in[6];
    float* out = (float*)d_out;

    char* ws   = (char*)d_ws;
    int*  col  = (int*)ws;                               // 1 MB
    short* W1T = (short*)(ws + 1048576);                 // 20480 B
    short* W2T = (short*)(ws + 1048576 + 20480);         // 65536 B

    prep_w<<<84, 64, 0, stream>>>(W1, W2, W1T, W2T);
    knn_kernel<<<NQ, 256, 0, stream>>>(pos, col, out);
    mlp_mfma<<<NQ/4, 256, 0, stream>>>(x, pos, col, b1, b2, W1T, W2T, out);
}